// Round 1
// baseline (476.315 us; speedup 1.0000x reference)
//
#include <hip/hip_runtime.h>
#include <hip/hip_bf16.h>

// ---- problem constants ----
#define BB 512
#define SS 49
#define DD 448
#define HH 8
#define QKVO 1536
#define MLPH 1792
#define MM (BB*SS)          // 25088 rows, 196 tiles of 128

using bf16_t = __hip_bfloat16;
typedef __attribute__((ext_vector_type(8))) short short8;   // bf16x8 MFMA frag
typedef __attribute__((ext_vector_type(4))) float f32x4;    // MFMA acc

__device__ __forceinline__ void gload_lds16(const void* g, void* l) {
  __builtin_amdgcn_global_load_lds(
      (const __attribute__((address_space(1))) void*)g,
      (__attribute__((address_space(3))) void*)l,
      16, 0, 0);
}

// ---------------- prep: transpose+cast weights to bf16, expand bias table ----------------
// sections: qkv_wT 1536x448 | proj_wT 448x1024 | w1T 1792x448 | w2T 448x1792 | bias 8x2401
__global__ void prep_kernel(const float* __restrict__ qkv_w, const float* __restrict__ proj_w,
                            const float* __restrict__ w1, const float* __restrict__ w2,
                            const float* __restrict__ ab, const int* __restrict__ idxs,
                            bf16_t* __restrict__ qkv_wT, bf16_t* __restrict__ proj_wT,
                            bf16_t* __restrict__ w1T, bf16_t* __restrict__ w2T,
                            float* __restrict__ bias_exp)
{
  int idx = blockIdx.x * 256 + threadIdx.x;
  if (idx < 688128) {                       // qkv_wT[n*448+k] = qkv_w[k*1536+n]
    int n = idx / 448, k = idx % 448;
    qkv_wT[idx] = __float2bfloat16(qkv_w[k*1536 + n]);
  } else if ((idx -= 688128) < 458752) {    // proj_wT[n*1024+k] = proj_w[k*448+n]
    int n = idx / 1024, k = idx % 1024;
    proj_wT[idx] = __float2bfloat16(proj_w[k*448 + n]);
  } else if ((idx -= 458752) < 802816) {    // w1T[n*448+k] = w1[k*1792+n]
    int n = idx / 448, k = idx % 448;
    w1T[idx] = __float2bfloat16(w1[k*1792 + n]);
  } else if ((idx -= 802816) < 802816) {    // w2T[n*1792+k] = w2[k*448+n]
    int n = idx / 1792, k = idx % 1792;
    w2T[idx] = __float2bfloat16(w2[k*448 + n]);
  } else if ((idx -= 802816) < 19208) {     // bias_exp[h*2401 + q*49 + k]
    int h = idx / 2401, i = idx % 2401;
    bias_exp[idx] = ab[h*49 + idxs[i]];
  }
}

// ---------------- layernorm: one wave per row of 448 ----------------
__global__ __launch_bounds__(256) void ln_kernel(const float* __restrict__ x,
                                                 const float* __restrict__ g,
                                                 const float* __restrict__ b,
                                                 bf16_t* __restrict__ out)
{
  const int w = threadIdx.x >> 6, lane = threadIdx.x & 63;
  const int row = blockIdx.x * 4 + w;
  const float* xr = x + (size_t)row * DD;
  float v[7];
  float s = 0.f;
#pragma unroll
  for (int j = 0; j < 7; ++j) { v[j] = xr[lane + 64*j]; s += v[j]; }
#pragma unroll
  for (int off = 32; off; off >>= 1) s += __shfl_xor(s, off, 64);
  const float mu = s * (1.0f/448.0f);
  float q = 0.f;
#pragma unroll
  for (int j = 0; j < 7; ++j) { float d = v[j] - mu; q += d*d; }
#pragma unroll
  for (int off = 32; off; off >>= 1) q += __shfl_xor(q, off, 64);
  const float rstd = rsqrtf(q * (1.0f/448.0f) + 1e-5f);
  bf16_t* orow = out + (size_t)row * DD;
#pragma unroll
  for (int j = 0; j < 7; ++j) {
    int c = lane + 64*j;
    orow[c] = __float2bfloat16((v[j] - mu) * rstd * g[c] + b[c]);
  }
}

// ---------------- bf16 GEMM: C = A(MxK) @ Bt(NxK)^T, fused epilogues ----------------
enum { EP_BF16 = 0, EP_RES1 = 1, EP_GELU = 2, EP_RES2 = 3 };

template<int EPI>
__global__ __launch_bounds__(256, 2) void gemm_bf16(
    const bf16_t* __restrict__ A, const bf16_t* __restrict__ Bt,
    const float* __restrict__ bias, const float* __restrict__ resid,
    const float* __restrict__ ls, bf16_t* __restrict__ Obf,
    float* __restrict__ Of, int N, int K)
{
  // LDS: A tile [128 rows][64 k] bf16 at 0; B tile [128 n][64 k] bf16 at 16384.
  // 16B chunks XOR-swizzled: slot = chunk ^ (row&7); source pre-swizzled so
  // global_load_lds' linear write lands swizzled (rule #21).
  __shared__ __align__(16) char lds[32768];
  const int t = threadIdx.x;
  const int lane = t & 63;
  const int w = t >> 6;
  const int m0 = blockIdx.x * 128;
  const int n0 = blockIdx.y * 128;
  const int fr = lane & 15;          // frag row (A) / col (B)
  const int fq = lane >> 4;          // k-quad
  const int wm = (w >> 1) * 64;
  const int wn = (w & 1) * 64;

  f32x4 acc[4][4];
#pragma unroll
  for (int i = 0; i < 4; ++i)
#pragma unroll
    for (int j = 0; j < 4; ++j)
      acc[i][j] = f32x4{0.f, 0.f, 0.f, 0.f};

  // staging: chunk c = i*256 + t; row = c>>3 = i*32 + (t>>3); slot = t&7
  const int rsub = t >> 3;                   // 0..31
  const int g8 = (t & 7) ^ (rsub & 7);       // logical k-chunk (swizzle inverse)
  const int wbase = (t & 192) * 16;          // wave-uniform LDS base (w*1024)
  const int nkt = K >> 6;

  for (int kt = 0; kt < nkt; ++kt) {
    const int k0 = kt << 6;
#pragma unroll
    for (int i = 0; i < 4; ++i) {
      const int ra = i*32 + rsub;
      gload_lds16(A + (size_t)(m0 + ra) * K + (k0 + g8*8), lds + i*4096 + wbase);
      int rb = n0 + i*32 + rsub;
      if (rb >= N) rb = N - 1;               // clamp pad rows (N=448 tiles)
      gload_lds16(Bt + (size_t)rb * K + (k0 + g8*8), lds + 16384 + i*4096 + wbase);
    }
    __syncthreads();
#pragma unroll
    for (int kk = 0; kk < 2; ++kk) {
      short8 af[4], bfr[4];
#pragma unroll
      for (int i = 0; i < 4; ++i) {
        const int ra = wm + i*16 + fr;
        const int ca = (fq + kk*4) ^ (ra & 7);
        af[i] = *(const short8*)(lds + ra*128 + ca*16);
        const int rb2 = wn + i*16 + fr;
        const int cb = (fq + kk*4) ^ (rb2 & 7);
        bfr[i] = *(const short8*)(lds + 16384 + rb2*128 + cb*16);
      }
#pragma unroll
      for (int mi = 0; mi < 4; ++mi)
#pragma unroll
        for (int ni = 0; ni < 4; ++ni)
          acc[mi][ni] = __builtin_amdgcn_mfma_f32_16x16x32_bf16(af[mi], bfr[ni], acc[mi][ni], 0, 0, 0);
    }
    __syncthreads();
  }

  // epilogue: D layout col = lane&15, row = (lane>>4)*4 + ri  [m89-verified]
#pragma unroll
  for (int mi = 0; mi < 4; ++mi) {
#pragma unroll
    for (int ni = 0; ni < 4; ++ni) {
      const int col = n0 + wn + ni*16 + fr;
      if (col < N) {
        const float bc = bias[col];
        const int row0 = m0 + wm + mi*16 + fq*4;
#pragma unroll
        for (int ri = 0; ri < 4; ++ri) {
          const size_t o = (size_t)(row0 + ri) * N + col;
          const float v = acc[mi][ni][ri] + bc;
          if constexpr (EPI == EP_BF16) {
            Obf[o] = __float2bfloat16(v);
          } else if constexpr (EPI == EP_GELU) {
            Obf[o] = __float2bfloat16(0.5f * v * (1.0f + erff(v * 0.7071067811865475f)));
          } else if constexpr (EPI == EP_RES1) {
            Of[o] = resid[o] + ls[col] * v;
          } else { // EP_RES2: in-place x1 += ls2 * mlp_out
            Of[o] = Of[o] + ls[col] * v;
          }
        }
      }
    }
  }
}

// ---------------- attention: one block per (b,h) ----------------
__global__ __launch_bounds__(256) void attn_kernel(const bf16_t* __restrict__ qkv,
                                                   const float* __restrict__ bias_exp,
                                                   bf16_t* __restrict__ ctx)
{
  __shared__ float Qs[49][32];
  __shared__ float Ks[49][33];   // +1 pad: kills stride-128B bank conflict in score dot
  __shared__ float Vs[49][128];
  __shared__ float Ps[49][49];
  const int b = blockIdx.x >> 3, h = blockIdx.x & 7;
  const int t = threadIdx.x;
  const size_t base = ((size_t)b * SS) * QKVO + h * 192;

  for (int idx = t; idx < 49*32; idx += 256) {
    const int s = idx >> 5, d = idx & 31;
    const size_t ro = base + (size_t)s * QKVO;
    Qs[s][d] = __bfloat162float(qkv[ro + d]);
    Ks[s][d] = __bfloat162float(qkv[ro + 32 + d]);
  }
  for (int idx = t; idx < 49*128; idx += 256) {
    const int s = idx >> 7, e = idx & 127;
    Vs[s][e] = __bfloat162float(qkv[base + (size_t)s * QKVO + 64 + e]);
  }
  __syncthreads();

  const float scale = 0.1767766952966369f;  // 32^-0.5
  const float* bh = bias_exp + h * 2401;
  for (int idx = t; idx < 2401; idx += 256) {
    const int i = idx / 49, j = idx % 49;
    float s = 0.f;
#pragma unroll
    for (int d = 0; d < 32; ++d) s += Qs[i][d] * Ks[j][d];
    Ps[i][j] = s * scale + bh[idx];
  }
  __syncthreads();

  const int w = t >> 6, lane = t & 63;
  for (int r = w; r < 49; r += 4) {
    float m = (lane < 49) ? Ps[r][lane] : -1e30f;
#pragma unroll
    for (int off = 32; off; off >>= 1) m = fmaxf(m, __shfl_xor(m, off, 64));
    float p = (lane < 49) ? __expf(Ps[r][lane] - m) : 0.f;
    float s = p;
#pragma unroll
    for (int off = 32; off; off >>= 1) s += __shfl_xor(s, off, 64);
    const float inv = 1.0f / s;
    if (lane < 49) Ps[r][lane] = p * inv;
  }
  __syncthreads();

  for (int idx = t; idx < 49*128; idx += 256) {
    const int i = idx >> 7, e = idx & 127;
    float s = 0.f;
#pragma unroll
    for (int j = 0; j < 49; ++j) s += Ps[i][j] * Vs[j][e];
    ctx[((size_t)b * SS + i) * 1024 + h * 128 + e] = __float2bfloat16(s);
  }
}

// ---------------- launch ----------------
extern "C" void kernel_launch(void* const* d_in, const int* in_sizes, int n_in,
                              void* d_out, int out_size, void* d_ws, size_t ws_size,
                              hipStream_t stream) {
  const float* x      = (const float*)d_in[0];
  const float* ln1_g  = (const float*)d_in[1];
  const float* ln1_b  = (const float*)d_in[2];
  const float* qkv_w  = (const float*)d_in[3];
  const float* qkv_b  = (const float*)d_in[4];
  const float* ab     = (const float*)d_in[5];
  const float* proj_w = (const float*)d_in[6];
  const float* proj_b = (const float*)d_in[7];
  const float* ln2_g  = (const float*)d_in[8];
  const float* ln2_b  = (const float*)d_in[9];
  const float* w1     = (const float*)d_in[10];
  const float* b1     = (const float*)d_in[11];
  const float* w2     = (const float*)d_in[12];
  const float* b2     = (const float*)d_in[13];
  const float* ls1    = (const float*)d_in[14];
  const float* ls2    = (const float*)d_in[15];
  const int*   idxs   = (const int*)d_in[16];
  float* out = (float*)d_out;
  char* ws = (char*)d_ws;

  // workspace layout (bytes, all 256-aligned)
  bf16_t* h_buf    = (bf16_t*)(ws);                       // 22,478,848  (h, then h2)
  bf16_t* qkv_buf  = (bf16_t*)(ws + 22478848);            // 77,070,336
  bf16_t* ctx_buf  = (bf16_t*)(ws + 99549184);            // 51,380,224
  bf16_t* m_buf    = (bf16_t*)(ws + 22478848);            // 89,915,392 (reuses qkv+ctx)
  bf16_t* qkv_wT   = (bf16_t*)(ws + 150929408);
  bf16_t* proj_wT  = (bf16_t*)(ws + 152305664);
  bf16_t* w1T      = (bf16_t*)(ws + 153223168);
  bf16_t* w2T      = (bf16_t*)(ws + 154828800);
  float*  bias_exp = (float*)(ws + 156434432);            // end 156,511,264

  const int prep_total = 688128 + 458752 + 802816 + 802816 + 19208;
  prep_kernel<<<(prep_total + 255)/256, 256, 0, stream>>>(
      qkv_w, proj_w, w1, w2, ab, idxs, qkv_wT, proj_wT, w1T, w2T, bias_exp);

  ln_kernel<<<MM/4, 256, 0, stream>>>(x, ln1_g, ln1_b, h_buf);

  gemm_bf16<EP_BF16><<<dim3(MM/128, 12), 256, 0, stream>>>(
      h_buf, qkv_wT, qkv_b, nullptr, nullptr, qkv_buf, nullptr, QKVO, DD);

  attn_kernel<<<BB*HH, 256, 0, stream>>>(qkv_buf, bias_exp, ctx_buf);

  gemm_bf16<EP_RES1><<<dim3(MM/128, 4), 256, 0, stream>>>(
      ctx_buf, proj_wT, proj_b, x, ls1, nullptr, out, DD, 1024);

  ln_kernel<<<MM/4, 256, 0, stream>>>(out, ln2_g, ln2_b, h_buf);

  gemm_bf16<EP_GELU><<<dim3(MM/128, 14), 256, 0, stream>>>(
      h_buf, w1T, b1, nullptr, nullptr, m_buf, nullptr, MLPH, DD);

  gemm_bf16<EP_RES2><<<dim3(MM/128, 4), 256, 0, stream>>>(
      m_buf, w2T, b2, nullptr, ls2, nullptr, out, DD, MLPH);
}

// Round 2
// 342.869 us; speedup vs baseline: 1.3892x; 1.3892x over previous
//
#include <hip/hip_runtime.h>
#include <hip/hip_bf16.h>

// ---- problem constants ----
#define BB 512
#define SS 49
#define DD 448
#define HH 8
#define QKVO 1536
#define MLPH 1792
#define MM (BB*SS)          // 25088 rows, 196 tiles of 128

using bf16_t = __hip_bfloat16;
typedef __attribute__((ext_vector_type(8))) short short8;   // bf16x8 MFMA frag
typedef __attribute__((ext_vector_type(4))) float f32x4;    // MFMA acc

__device__ __forceinline__ void gload_lds16(const void* g, void* l) {
  __builtin_amdgcn_global_load_lds(
      (const __attribute__((address_space(1))) void*)g,
      (__attribute__((address_space(3))) void*)l,
      16, 0, 0);
}

// ---------------- prep: transpose+cast weights to bf16, expand bias table ----------------
// sections: qkv_wT 1536x448 | proj_wT 448x1024 | w1T 1792x448 | w2T 448x1792 | bias_pad 8x64x64 bf16
__global__ void prep_kernel(const float* __restrict__ qkv_w, const float* __restrict__ proj_w,
                            const float* __restrict__ w1, const float* __restrict__ w2,
                            const float* __restrict__ ab, const int* __restrict__ idxs,
                            bf16_t* __restrict__ qkv_wT, bf16_t* __restrict__ proj_wT,
                            bf16_t* __restrict__ w1T, bf16_t* __restrict__ w2T,
                            bf16_t* __restrict__ bias_pad)
{
  int idx = blockIdx.x * 256 + threadIdx.x;
  if (idx < 688128) {                       // qkv_wT[n*448+k] = qkv_w[k*1536+n]
    int n = idx / 448, k = idx % 448;
    qkv_wT[idx] = __float2bfloat16(qkv_w[k*1536 + n]);
  } else if ((idx -= 688128) < 458752) {    // proj_wT[n*1024+k] = proj_w[k*448+n]
    int n = idx / 1024, k = idx % 1024;
    proj_wT[idx] = __float2bfloat16(proj_w[k*448 + n]);
  } else if ((idx -= 458752) < 802816) {    // w1T[n*448+k] = w1[k*1792+n]
    int n = idx / 448, k = idx % 448;
    w1T[idx] = __float2bfloat16(w1[k*1792 + n]);
  } else if ((idx -= 802816) < 802816) {    // w2T[n*1792+k] = w2[k*448+n]
    int n = idx / 1792, k = idx % 1792;
    w2T[idx] = __float2bfloat16(w2[k*448 + n]);
  } else if ((idx -= 802816) < 32768) {     // bias_pad[h][r][c], pad = -1e30
    int h = idx >> 12, r = (idx >> 6) & 63, c = idx & 63;
    float v = (r < SS && c < SS) ? ab[h*49 + idxs[r*49 + c]] : -1e30f;
    bias_pad[idx] = __float2bfloat16(v);
  }
}

// ---------------- layernorm: one wave per row of 448 ----------------
__global__ __launch_bounds__(256) void ln_kernel(const float* __restrict__ x,
                                                 const float* __restrict__ g,
                                                 const float* __restrict__ b,
                                                 bf16_t* __restrict__ out)
{
  const int w = threadIdx.x >> 6, lane = threadIdx.x & 63;
  const int row = blockIdx.x * 4 + w;
  const float* xr = x + (size_t)row * DD;
  float v[7];
  float s = 0.f;
#pragma unroll
  for (int j = 0; j < 7; ++j) { v[j] = xr[lane + 64*j]; s += v[j]; }
#pragma unroll
  for (int off = 32; off; off >>= 1) s += __shfl_xor(s, off, 64);
  const float mu = s * (1.0f/448.0f);
  float q = 0.f;
#pragma unroll
  for (int j = 0; j < 7; ++j) { float d = v[j] - mu; q += d*d; }
#pragma unroll
  for (int off = 32; off; off >>= 1) q += __shfl_xor(q, off, 64);
  const float rstd = rsqrtf(q * (1.0f/448.0f) + 1e-5f);
  bf16_t* orow = out + (size_t)row * DD;
#pragma unroll
  for (int j = 0; j < 7; ++j) {
    int c = lane + 64*j;
    orow[c] = __float2bfloat16((v[j] - mu) * rstd * g[c] + b[c]);
  }
}

// ---------------- bf16 GEMM: C = A(MxK) @ Bt(NxK)^T, fused epilogues ----------------
enum { EP_BF16 = 0, EP_RES1 = 1, EP_GELU = 2, EP_RES2 = 3 };

template<int EPI>
__global__ __launch_bounds__(256, 2) void gemm_bf16(
    const bf16_t* __restrict__ A, const bf16_t* __restrict__ Bt,
    const float* __restrict__ bias, const float* __restrict__ resid,
    const float* __restrict__ ls, bf16_t* __restrict__ Obf,
    float* __restrict__ Of, int N, int K)
{
  __shared__ __align__(16) char lds[32768];
  const int t = threadIdx.x;
  const int lane = t & 63;
  const int w = t >> 6;
  const int m0 = blockIdx.x * 128;
  const int n0 = blockIdx.y * 128;
  const int fr = lane & 15;          // frag row (A) / col (B)
  const int fq = lane >> 4;          // k-quad
  const int wm = (w >> 1) * 64;
  const int wn = (w & 1) * 64;

  f32x4 acc[4][4];
#pragma unroll
  for (int i = 0; i < 4; ++i)
#pragma unroll
    for (int j = 0; j < 4; ++j)
      acc[i][j] = f32x4{0.f, 0.f, 0.f, 0.f};

  const int rsub = t >> 3;                   // 0..31
  const int g8 = (t & 7) ^ (rsub & 7);       // logical k-chunk (swizzle inverse)
  const int wbase = (t & 192) * 16;          // wave-uniform LDS base (w*1024)
  const int nkt = K >> 6;

  for (int kt = 0; kt < nkt; ++kt) {
    const int k0 = kt << 6;
#pragma unroll
    for (int i = 0; i < 4; ++i) {
      const int ra = i*32 + rsub;
      gload_lds16(A + (size_t)(m0 + ra) * K + (k0 + g8*8), lds + i*4096 + wbase);
      int rb = n0 + i*32 + rsub;
      if (rb >= N) rb = N - 1;               // clamp pad rows (N=448 tiles)
      gload_lds16(Bt + (size_t)rb * K + (k0 + g8*8), lds + 16384 + i*4096 + wbase);
    }
    __syncthreads();
#pragma unroll
    for (int kk = 0; kk < 2; ++kk) {
      short8 af[4], bfr[4];
#pragma unroll
      for (int i = 0; i < 4; ++i) {
        const int ra = wm + i*16 + fr;
        const int ca = (fq + kk*4) ^ (ra & 7);
        af[i] = *(const short8*)(lds + ra*128 + ca*16);
        const int rb2 = wn + i*16 + fr;
        const int cb = (fq + kk*4) ^ (rb2 & 7);
        bfr[i] = *(const short8*)(lds + 16384 + rb2*128 + cb*16);
      }
#pragma unroll
      for (int mi = 0; mi < 4; ++mi)
#pragma unroll
        for (int ni = 0; ni < 4; ++ni)
          acc[mi][ni] = __builtin_amdgcn_mfma_f32_16x16x32_bf16(af[mi], bfr[ni], acc[mi][ni], 0, 0, 0);
    }
    __syncthreads();
  }

#pragma unroll
  for (int mi = 0; mi < 4; ++mi) {
#pragma unroll
    for (int ni = 0; ni < 4; ++ni) {
      const int col = n0 + wn + ni*16 + fr;
      if (col < N) {
        const float bc = bias[col];
        const int row0 = m0 + wm + mi*16 + fq*4;
#pragma unroll
        for (int ri = 0; ri < 4; ++ri) {
          const size_t o = (size_t)(row0 + ri) * N + col;
          const float v = acc[mi][ni][ri] + bc;
          if constexpr (EPI == EP_BF16) {
            Obf[o] = __float2bfloat16(v);
          } else if constexpr (EPI == EP_GELU) {
            Obf[o] = __float2bfloat16(0.5f * v * (1.0f + erff(v * 0.7071067811865475f)));
          } else if constexpr (EPI == EP_RES1) {
            Of[o] = resid[o] + ls[col] * v;
          } else { // EP_RES2
            Of[o] = Of[o] + ls[col] * v;
          }
        }
      }
    }
  }
}

// ---------------- attention via MFMA: one wave per (b,h) ----------------
__global__ __launch_bounds__(64) void attn_mfma_kernel(const bf16_t* __restrict__ qkv,
                                                       const bf16_t* __restrict__ bias_pad,
                                                       bf16_t* __restrict__ ctx)
{
  // Vs: [64 j][16 chunks of 8 e] bf16, chunk XOR-swizzled by (j>>3) to kill
  // the j-strided gather bank conflict. Ps: [64 q][72] bf16 (stride 144B).
  __shared__ __align__(16) bf16_t VsF[64*128];
  __shared__ __align__(16) bf16_t PsF[64*72];
  const int b = blockIdx.x >> 3, h = blockIdx.x & 7;
  const int l = threadIdx.x;
  const int fr = l & 15, g = l >> 4;
  const size_t base = ((size_t)b * SS) * QKVO + (size_t)h * 192;

  // ---- stage V (rows >= 49 duplicate row 48: finite, and P there is exactly 0)
  for (int c = l; c < 1024; c += 64) {
    const int j = c >> 4, ch = c & 15;
    const int jc = j < SS ? j : SS - 1;
    short8 v = *(const short8*)(qkv + base + (size_t)jc * QKVO + 64 + ch*8);
    *(short8*)(&VsF[j*128 + ((ch ^ (j >> 3)) & 15)*8]) = v;
  }

  // ---- QK^T: fragments straight from global (row-major [s][32] == frag layout)
  short8 qf[4], kf[4];
#pragma unroll
  for (int mi = 0; mi < 4; ++mi) {
    int qr = mi*16 + fr; if (qr > SS-1) qr = SS-1;
    qf[mi] = *(const short8*)(qkv + base + (size_t)qr * QKVO + g*8);
    int kr = mi*16 + fr; if (kr > SS-1) kr = SS-1;
    kf[mi] = *(const short8*)(qkv + base + (size_t)kr * QKVO + 32 + g*8);
  }
  f32x4 sc[4][4];
#pragma unroll
  for (int mi = 0; mi < 4; ++mi)
#pragma unroll
    for (int ni = 0; ni < 4; ++ni)
      sc[mi][ni] = f32x4{0.f,0.f,0.f,0.f};
#pragma unroll
  for (int mi = 0; mi < 4; ++mi)
#pragma unroll
    for (int ni = 0; ni < 4; ++ni)
      sc[mi][ni] = __builtin_amdgcn_mfma_f32_16x16x32_bf16(qf[mi], kf[ni], sc[mi][ni], 0, 0, 0);

  // ---- scale + bias + row softmax (rows live in 16-lane groups)
  const float scale = 0.17677669529663687f;   // 32^-0.5
  const bf16_t* bp = bias_pad + (size_t)h * 4096;
#pragma unroll
  for (int mi = 0; mi < 4; ++mi) {
#pragma unroll
    for (int ri = 0; ri < 4; ++ri) {
      const int r = mi*16 + g*4 + ri;
      float v0 = sc[mi][0][ri]*scale + __bfloat162float(bp[r*64 +      fr]);
      float v1 = sc[mi][1][ri]*scale + __bfloat162float(bp[r*64 + 16 + fr]);
      float v2 = sc[mi][2][ri]*scale + __bfloat162float(bp[r*64 + 32 + fr]);
      float v3 = sc[mi][3][ri]*scale + __bfloat162float(bp[r*64 + 48 + fr]);
      float m = fmaxf(fmaxf(v0, v1), fmaxf(v2, v3));
#pragma unroll
      for (int off = 8; off; off >>= 1) m = fmaxf(m, __shfl_xor(m, off, 64));
      v0 = __expf(v0 - m); v1 = __expf(v1 - m);
      v2 = __expf(v2 - m); v3 = __expf(v3 - m);
      float s = v0 + v1 + v2 + v3;
#pragma unroll
      for (int off = 8; off; off >>= 1) s += __shfl_xor(s, off, 64);
      const float inv = 1.0f / s;
      PsF[r*72 +      fr] = __float2bfloat16(v0 * inv);
      PsF[r*72 + 16 + fr] = __float2bfloat16(v1 * inv);
      PsF[r*72 + 32 + fr] = __float2bfloat16(v2 * inv);
      PsF[r*72 + 48 + fr] = __float2bfloat16(v3 * inv);
    }
  }
  __syncthreads();

  // ---- PV: A = P (LDS b128 frags), B = V (swizzled scalar gather)
  short8 pf[4][2];
#pragma unroll
  for (int mi = 0; mi < 4; ++mi)
#pragma unroll
    for (int ks = 0; ks < 2; ++ks)
      pf[mi][ks] = *(const short8*)(&PsF[(mi*16 + fr)*72 + ks*32 + g*8]);

#pragma unroll
  for (int ni = 0; ni < 8; ++ni) {
    const int e = ni*16 + fr;
    short8 vf[2];
#pragma unroll
    for (int ks = 0; ks < 2; ++ks) {
      const int jb = ks*32 + g*8;
#pragma unroll
      for (int jj = 0; jj < 8; ++jj) {
        const int j = jb + jj;
        const int ch = ((e >> 3) ^ (j >> 3)) & 15;
        vf[ks][jj] = *(const short*)(&VsF[j*128 + ch*8 + (e & 7)]);
      }
    }
    f32x4 acc2[4];
#pragma unroll
    for (int mi = 0; mi < 4; ++mi) acc2[mi] = f32x4{0.f,0.f,0.f,0.f};
#pragma unroll
    for (int ks = 0; ks < 2; ++ks)
#pragma unroll
      for (int mi = 0; mi < 4; ++mi)
        acc2[mi] = __builtin_amdgcn_mfma_f32_16x16x32_bf16(pf[mi][ks], vf[ks], acc2[mi], 0, 0, 0);
#pragma unroll
    for (int mi = 0; mi < 4; ++mi) {
#pragma unroll
      for (int ri = 0; ri < 4; ++ri) {
        const int q = mi*16 + g*4 + ri;
        if (q < SS)
          ctx[((size_t)b * SS + q) * 1024 + h*128 + e] = __float2bfloat16(acc2[mi][ri]);
      }
    }
  }
}

// ---------------- launch ----------------
extern "C" void kernel_launch(void* const* d_in, const int* in_sizes, int n_in,
                              void* d_out, int out_size, void* d_ws, size_t ws_size,
                              hipStream_t stream) {
  const float* x      = (const float*)d_in[0];
  const float* ln1_g  = (const float*)d_in[1];
  const float* ln1_b  = (const float*)d_in[2];
  const float* qkv_w  = (const float*)d_in[3];
  const float* qkv_b  = (const float*)d_in[4];
  const float* ab     = (const float*)d_in[5];
  const float* proj_w = (const float*)d_in[6];
  const float* proj_b = (const float*)d_in[7];
  const float* ln2_g  = (const float*)d_in[8];
  const float* ln2_b  = (const float*)d_in[9];
  const float* w1     = (const float*)d_in[10];
  const float* b1     = (const float*)d_in[11];
  const float* w2     = (const float*)d_in[12];
  const float* b2     = (const float*)d_in[13];
  const float* ls1    = (const float*)d_in[14];
  const float* ls2    = (const float*)d_in[15];
  const int*   idxs   = (const int*)d_in[16];
  float* out = (float*)d_out;
  char* ws = (char*)d_ws;

  // workspace layout (bytes, all 256-aligned)
  bf16_t* h_buf    = (bf16_t*)(ws);                       // 22,478,848  (h, then h2)
  bf16_t* qkv_buf  = (bf16_t*)(ws + 22478848);            // 77,070,336
  bf16_t* ctx_buf  = (bf16_t*)(ws + 99549184);            // 51,380,224
  bf16_t* m_buf    = (bf16_t*)(ws + 22478848);            // 89,915,392 (reuses qkv+ctx)
  bf16_t* qkv_wT   = (bf16_t*)(ws + 150929408);
  bf16_t* proj_wT  = (bf16_t*)(ws + 152305664);
  bf16_t* w1T      = (bf16_t*)(ws + 153223168);
  bf16_t* w2T      = (bf16_t*)(ws + 154828800);
  bf16_t* bias_pad = (bf16_t*)(ws + 156434432);           // 65,536 -> end 156,499,968

  const int prep_total = 688128 + 458752 + 802816 + 802816 + 32768;
  prep_kernel<<<(prep_total + 255)/256, 256, 0, stream>>>(
      qkv_w, proj_w, w1, w2, ab, idxs, qkv_wT, proj_wT, w1T, w2T, bias_pad);

  ln_kernel<<<MM/4, 256, 0, stream>>>(x, ln1_g, ln1_b, h_buf);

  gemm_bf16<EP_BF16><<<dim3(MM/128, 12), 256, 0, stream>>>(
      h_buf, qkv_wT, qkv_b, nullptr, nullptr, qkv_buf, nullptr, QKVO, DD);

  attn_mfma_kernel<<<BB*HH, 64, 0, stream>>>(qkv_buf, bias_pad, ctx_buf);

  gemm_bf16<EP_RES1><<<dim3(MM/128, 4), 256, 0, stream>>>(
      ctx_buf, proj_wT, proj_b, x, ls1, nullptr, out, DD, 1024);

  ln_kernel<<<MM/4, 256, 0, stream>>>(out, ln2_g, ln2_b, h_buf);

  gemm_bf16<EP_GELU><<<dim3(MM/128, 14), 256, 0, stream>>>(
      h_buf, w1T, b1, nullptr, nullptr, m_buf, nullptr, MLPH, DD);

  gemm_bf16<EP_RES2><<<dim3(MM/128, 4), 256, 0, stream>>>(
      m_buf, w2T, b2, nullptr, ls2, nullptr, out, DD, MLPH);
}